// Round 2
// baseline (342.297 us; speedup 1.0000x reference)
//
#include <hip/hip_runtime.h>
#include <math.h>

#define S_ 2048
#define E_ 2048
#define H_ 16
#define D_ 128

typedef _Float16 f16;
typedef _Float16 f16x8 __attribute__((ext_vector_type(8)));
typedef _Float16 f16x4 __attribute__((ext_vector_type(4)));
typedef float f32x4 __attribute__((ext_vector_type(4)));

// async global->LDS, 16B per lane. LDS dest must be wave-uniform base + lane*16.
// Used ONLY in the m97-pattern GEMMs (issue -> barrier -> consume, adjacent).
#define GLDS(g, l)                                                            \
    __builtin_amdgcn_global_load_lds(                                         \
        (const __attribute__((address_space(1))) void*)(g),                   \
        (__attribute__((address_space(3))) void*)(l), 16, 0, 0)

// ---------------------------------------------------------------- convert
__global__ __launch_bounds__(256) void cvt_f32_f16(const float* __restrict__ in,
                                                   f16* __restrict__ out, int n) {
    int i = (blockIdx.x * 256 + threadIdx.x) * 4;
    if (i + 3 < n) {
        float4 v = *(const float4*)(in + i);
        f16x4 o;
        o[0] = (f16)v.x; o[1] = (f16)v.y; o[2] = (f16)v.z; o[3] = (f16)v.w;
        *(f16x4*)(out + i) = o;
    }
}

// ---------------------------------------------------------------- QKV GEMM (m97 structure)
__global__ __launch_bounds__(256) void gemm_qkv(const f16* __restrict__ A,
                                                const f16* __restrict__ B,
                                                const float* __restrict__ bias,
                                                f16* __restrict__ Qm,
                                                f16* __restrict__ Km,
                                                f16* __restrict__ VTm) {
    __shared__ __align__(16) f16 As[128 * 32];   // unpadded: required by global_load_lds
    __shared__ __align__(16) f16 Bs[128 * 32];
    const int tid  = threadIdx.x;
    const int lane = tid & 63, wave = tid >> 6;
    const int lm = lane & 15, quad = lane >> 4;
    const int wm = wave >> 1, wn = wave & 1;
    const int tn0 = blockIdx.x * 128;
    const int tm0 = blockIdx.y * 128;

    const int srow = tid >> 2, scol = (tid & 3) * 8;
    const f16* Ag0 = A + (size_t)(tm0 + srow) * E_ + scol;
    const f16* Ag1 = Ag0 + (size_t)64 * E_;
    const f16* Bg0 = B + (size_t)(tn0 + srow) * E_ + scol;
    const f16* Bg1 = Bg0 + (size_t)64 * E_;
    f16* Al0 = &As[tid * 8];
    f16* Al1 = &As[(256 + tid) * 8];
    f16* Bl0 = &Bs[tid * 8];
    f16* Bl1 = &Bs[(256 + tid) * 8];

    const f32x4 vzero = {0.f, 0.f, 0.f, 0.f};
    f32x4 acc[4][4];
#pragma unroll
    for (int i = 0; i < 4; i++)
#pragma unroll
        for (int j = 0; j < 4; j++) acc[i][j] = vzero;

    for (int k0 = 0; k0 < E_; k0 += 32) {
        __syncthreads();
        GLDS(Ag0 + k0, Al0); GLDS(Ag1 + k0, Al1);
        GLDS(Bg0 + k0, Bl0); GLDS(Bg1 + k0, Bl1);
        __syncthreads();
        f16x8 af[4], bfr[4];
#pragma unroll
        for (int i = 0; i < 4; i++)
            af[i] = *(const f16x8*)&As[(wm * 64 + i * 16 + lm) * 32 + quad * 8];
#pragma unroll
        for (int j = 0; j < 4; j++)
            bfr[j] = *(const f16x8*)&Bs[(wn * 64 + j * 16 + lm) * 32 + quad * 8];
#pragma unroll
        for (int i = 0; i < 4; i++)
#pragma unroll
            for (int j = 0; j < 4; j++)
                acc[i][j] = __builtin_amdgcn_mfma_f32_16x16x32_f16(af[i], bfr[j],
                                                                   acc[i][j], 0, 0, 0);
    }

    const float qscale = 0.08838834764831845f;  // 1/sqrt(128), prefolded into Q
#pragma unroll
    for (int i = 0; i < 4; i++) {
#pragma unroll
        for (int j = 0; j < 4; j++) {
            const int n = tn0 + wn * 64 + j * 16 + lm;
            const int which = n >> 11;
            const int h = (n >> 7) & 15;
            const int d = n & 127;
            const float bv = bias[n];
#pragma unroll
            for (int r = 0; r < 4; r++) {
                const int m = tm0 + wm * 64 + i * 16 + quad * 4 + r;
                float fv = acc[i][j][r] + bv;
                if (which == 0)      Qm[((size_t)h * S_ + m) * D_ + d] = (f16)(fv * qscale);
                else if (which == 1) Km[((size_t)h * S_ + m) * D_ + d] = (f16)fv;
                else                 VTm[((size_t)h * D_ + d) * S_ + m] = (f16)fv;
            }
        }
    }
}

// ---------------------------------------------------------------- attention (partial)
// Flash-decode decomposition for occupancy: work unit = (head, 64-row q-tile,
// kv-segment of 8 tiles = 512 keys). 1280 uniform blocks (<=8 iters each) vs
// the old 512 blocks of 1..32 iters whose tail ran 1 wave/SIMD.
// LDS = 40960B exactly -> 4 blocks/CU resident (16 waves/CU; 5th queued).
// Ps uses stride-64 + XOR swizzle (write f16x4 / read f16x8, same involution).
// Grid mapping: h = bx&15 pins each head pair to one XCD (K+V 2MB < 4MB L2);
// u = 79-(bx>>4) dispatches heavy segments first.
// qt<8 (single segment): writes Om directly. Else: unnormalized O (f16) + per-row
// (m,l) partials into dead xb/wqb workspace; attn_merge combines <=4 segments.
__global__ __launch_bounds__(256, 4) void attn_part(const f16* __restrict__ Qm,
                                                    const f16* __restrict__ Km,
                                                    const f16* __restrict__ VTm,
                                                    f16* __restrict__ Om,
                                                    f16* __restrict__ Opart,
                                                    float2* __restrict__ Mlp) {
    __shared__ __align__(16) f16 Ks[64 * 128];    // [key][d-chunk swizzled]
    __shared__ __align__(16) f16 VTs[128 * 64];   // [d][key-chunk swizzled]
    __shared__ __align__(16) f16 Ps[4][16 * 64];  // per-wave P, XOR-swizzled

    const int tid  = threadIdx.x;
    const int lane = tid & 63, wave = tid >> 6;
    const int lm = lane & 15, quad = lane >> 4;
    const int bx = blockIdx.x;
    const int h  = bx & 15;
    const int u  = 79 - (bx >> 4);   // canonical unit index, heavy-first dispatch

    int qt, seg;
    if (u < 8)       { qt = u;                  seg = 0; }
    else if (u < 24) { qt = 8  + ((u - 8) >> 1);  seg = (u - 8) & 1; }
    else if (u < 48) { qt = 16 + (u - 24) / 3;    seg = (u - 24) % 3; }
    else             { qt = 24 + ((u - 48) >> 2); seg = (u - 48) & 3; }
    const int t0 = seg * 8;
    const int t1 = (t0 + 8 < qt + 1) ? (t0 + 8) : (qt + 1);

    const f16* KmH  = Km  + (size_t)h * S_ * D_;
    const f16* VTmH = VTm + (size_t)h * D_ * S_;
    const f16* QmH  = Qm  + (size_t)h * S_ * D_;

    // staging assignment: 4 Ks chunks + 4 VTs chunks of 16B per thread.
    // global offsets linear (coalesced); LDS offsets XOR-swizzled.
    int kg[4], kl[4], vg[4], vl[4];
#pragma unroll
    for (int rr = 0; rr < 4; rr++) {
        int c = rr * 256 + tid;
        int key = c >> 4, dc = c & 15;
        kg[rr] = key * 128 + dc * 8;
        kl[rr] = key * 128 + ((dc & 8) | ((dc & 7) ^ (key & 7))) * 8;
        int d = c >> 3, sc = c & 7;
        vg[rr] = d * 2048 + sc * 8;
        vl[rr] = d * 64 + (sc ^ (d & 7)) * 8;
    }

    const f32x4 vzero = {0.f, 0.f, 0.f, 0.f};
    f32x4 o[8];
#pragma unroll
    for (int f = 0; f < 8; f++) o[f] = vzero;
    float mi = -INFINITY, li = 0.f;

    const int q0c = qt * 64 + wave * 16;           // this wave's 16-row chunk
    f16x8 qf[4];
#pragma unroll
    for (int kc = 0; kc < 4; kc++)
        qf[kc] = *(const f16x8*)(QmH + (size_t)(q0c + lm) * D_ + kc * 32 + quad * 8);

    // prefetch first tile of this segment into registers
    float4 kreg[4], vreg[4];
#pragma unroll
    for (int rr = 0; rr < 4; rr++) {
        kreg[rr] = *(const float4*)(KmH + (size_t)t0 * 8192 + kg[rr]);
        vreg[rr] = *(const float4*)(VTmH + t0 * 64 + vg[rr]);
    }

    char* psb = (char*)&Ps[wave][0];
    const int swz = (lm & 7) << 4;

    for (int t = t0; t < t1; t++) {
        const int k0 = t * 64;

        __syncthreads();   // all waves done READING LDS from previous iter
#pragma unroll
        for (int rr = 0; rr < 4; rr++) {
            *(float4*)&Ks[kl[rr]] = kreg[rr];
            *(float4*)&VTs[vl[rr]] = vreg[rr];
        }
        if (t + 1 < t1) {   // prefetch next tile; latency hides behind compute (TLP)
            const int nt = t + 1;
#pragma unroll
            for (int rr = 0; rr < 4; rr++) {
                kreg[rr] = *(const float4*)(KmH + (size_t)nt * 8192 + kg[rr]);
                vreg[rr] = *(const float4*)(VTmH + nt * 64 + vg[rr]);
            }
        }
        __syncthreads();   // ds_writes visible

        // ---- S^T = K * Q^T : C[m=key][n=qrow]
        f32x4 sfr[4];
        __builtin_amdgcn_s_setprio(1);
#pragma unroll
        for (int j = 0; j < 4; j++) {
            f32x4 a = vzero;
#pragma unroll
            for (int kc = 0; kc < 4; kc++) {
                int dc = kc * 4 + quad;
                int sc = (dc & 8) | ((dc & 7) ^ (lm & 7));
                f16x8 kf = *(const f16x8*)&Ks[(j * 16 + lm) * 128 + sc * 8];
                a = __builtin_amdgcn_mfma_f32_16x16x32_f16(kf, qf[kc], a, 0, 0, 0);
            }
            sfr[j] = a;
        }
        __builtin_amdgcn_s_setprio(0);

        // ---- online softmax (qrow = q0c+lm; 16 key-scores per lane)
        const bool masked = (t == qt);
        const int qrow = q0c + lm;
        float sv[4][4];
        float vmax = -3e38f;
#pragma unroll
        for (int j = 0; j < 4; j++)
#pragma unroll
            for (int r = 0; r < 4; r++) {
                float x = sfr[j][r];
                if (masked) {
                    int key = k0 + j * 16 + quad * 4 + r;
                    if (key > qrow) x = -1e30f;
                }
                sv[j][r] = x;
                vmax = fmaxf(vmax, x);
            }
        vmax = fmaxf(vmax, __shfl_xor(vmax, 16));
        vmax = fmaxf(vmax, __shfl_xor(vmax, 32));
        const float mn = fmaxf(mi, vmax);
        const float alpha = __expf(mi - mn);
        mi = mn;
        float rsum = 0.f;
#pragma unroll
        for (int j = 0; j < 4; j++) {
            f16x4 pk;
#pragma unroll
            for (int r = 0; r < 4; r++) {
                float pv = __expf(sv[j][r] - mn);
                rsum += pv;
                pk[r] = (f16)pv;
            }
            *(f16x4*)(psb + lm * 128 + ((j * 32 + quad * 8) ^ swz)) = pk;
        }
        rsum += __shfl_xor(rsum, 16);
        rsum += __shfl_xor(rsum, 32);
        li = li * alpha + rsum;
#pragma unroll
        for (int f = 0; f < 8; f++) {
            o[f][0] *= alpha; o[f][1] *= alpha; o[f][2] *= alpha; o[f][3] *= alpha;
        }

        // ---- O^T += V^T * P^T  (P read back same-wave: in-order LDS, no barrier)
        f16x8 pb[2];
#pragma unroll
        for (int kc = 0; kc < 2; kc++)
            pb[kc] = *(const f16x8*)(psb + lm * 128 + ((kc * 64 + quad * 16) ^ swz));
        __builtin_amdgcn_s_setprio(1);
#pragma unroll
        for (int f = 0; f < 8; f++) {
#pragma unroll
            for (int kc = 0; kc < 2; kc++) {
                int sc = (kc * 4 + quad) ^ (lm & 7);
                f16x8 vf = *(const f16x8*)&VTs[(f * 16 + lm) * 64 + sc * 8];
                o[f] = __builtin_amdgcn_mfma_f32_16x16x32_f16(vf, pb[kc], o[f], 0, 0, 0);
            }
        }
        __builtin_amdgcn_s_setprio(0);
    }

    if (qt < 8) {
        // single segment: normalized output directly
        const float inv = 1.f / li;
#pragma unroll
        for (int f = 0; f < 8; f++) {
            f16x4 ov;
#pragma unroll
            for (int r = 0; r < 4; r++) ov[r] = (f16)(o[f][r] * inv);
            *(f16x4*)(Om + (size_t)(q0c + lm) * E_ + h * 128 + f * 16 + quad * 4) = ov;
        }
    } else {
        // partial: unnormalized O (f16) + per-row (m, l)
        const int unit = h * 80 + u;
        f16* op = Opart + (size_t)unit * 8192 + (wave * 16 + lm) * 128;
#pragma unroll
        for (int f = 0; f < 8; f++) {
            f16x4 ov;
#pragma unroll
            for (int r = 0; r < 4; r++) ov[r] = (f16)o[f][r];
            *(f16x4*)(op + f * 16 + quad * 4) = ov;
        }
        if (quad == 0) Mlp[unit * 64 + wave * 16 + lm] = make_float2(mi, li);
    }
}

// ---------------------------------------------------------------- attention merge
// Combines <=4 kv-segment partials per (head, q-row) for rows >= 512.
// Memory-bound: ~19MB in (L2-warm), ~3MB out.
__global__ __launch_bounds__(256) void attn_merge(const f16* __restrict__ Opart,
                                                  const float2* __restrict__ Mlp,
                                                  f16* __restrict__ Om) {
    const int idx = blockIdx.x * 256 + threadIdx.x;   // 786432 total
    const int d4  = idx & 31;
    const int h   = (idx >> 5) & 15;
    const int r5  = idx >> 9;            // 0..1535
    const int row = 512 + r5;
    const int qt  = row >> 6;            // 8..31
    const int rw  = row & 63;
    const int nseg = (qt >> 3) + 1;      // 2..4
    int ub;
    if (qt < 16)      ub = 8  + 2 * (qt - 8);
    else if (qt < 24) ub = 24 + 3 * (qt - 16);
    else              ub = 48 + 4 * (qt - 24);
    const int base_unit = h * 80 + ub;

    float m = -INFINITY;
    for (int s = 0; s < nseg; s++)
        m = fmaxf(m, Mlp[(base_unit + s) * 64 + rw].x);

    float L = 0.f;
    float a0 = 0.f, a1 = 0.f, a2 = 0.f, a3 = 0.f;
    for (int s = 0; s < nseg; s++) {
        float2 ml = Mlp[(base_unit + s) * 64 + rw];
        float w = __expf(ml.x - m);
        L += w * ml.y;
        f16x4 ov = *(const f16x4*)(Opart + (size_t)(base_unit + s) * 8192 + rw * 128 + d4 * 4);
        a0 += w * (float)ov[0];
        a1 += w * (float)ov[1];
        a2 += w * (float)ov[2];
        a3 += w * (float)ov[3];
    }
    const float inv = 1.f / L;
    f16x4 res;
    res[0] = (f16)(a0 * inv); res[1] = (f16)(a1 * inv);
    res[2] = (f16)(a2 * inv); res[3] = (f16)(a3 * inv);
    *(f16x4*)(Om + (size_t)row * E_ + h * 128 + d4 * 4) = res;
}

// ---------------------------------------------------------------- out GEMM (m97 structure)
__global__ __launch_bounds__(256) void gemm_out(const f16* __restrict__ A,
                                                const f16* __restrict__ B,
                                                const float* __restrict__ bias,
                                                float* __restrict__ Cout) {
    __shared__ __align__(16) f16 As[128 * 32];
    __shared__ __align__(16) f16 Bs[128 * 32];
    const int tid  = threadIdx.x;
    const int lane = tid & 63, wave = tid >> 6;
    const int lm = lane & 15, quad = lane >> 4;
    const int wm = wave >> 1, wn = wave & 1;
    const int tn0 = blockIdx.x * 128;
    const int tm0 = blockIdx.y * 128;

    const int srow = tid >> 2, scol = (tid & 3) * 8;
    const f16* Ag0 = A + (size_t)(tm0 + srow) * E_ + scol;
    const f16* Ag1 = Ag0 + (size_t)64 * E_;
    const f16* Bg0 = B + (size_t)(tn0 + srow) * E_ + scol;
    const f16* Bg1 = Bg0 + (size_t)64 * E_;
    f16* Al0 = &As[tid * 8];
    f16* Al1 = &As[(256 + tid) * 8];
    f16* Bl0 = &Bs[tid * 8];
    f16* Bl1 = &Bs[(256 + tid) * 8];

    const f32x4 vzero = {0.f, 0.f, 0.f, 0.f};
    f32x4 acc[4][4];
#pragma unroll
    for (int i = 0; i < 4; i++)
#pragma unroll
        for (int j = 0; j < 4; j++) acc[i][j] = vzero;

    for (int k0 = 0; k0 < E_; k0 += 32) {
        __syncthreads();
        GLDS(Ag0 + k0, Al0); GLDS(Ag1 + k0, Al1);
        GLDS(Bg0 + k0, Bl0); GLDS(Bg1 + k0, Bl1);
        __syncthreads();
        f16x8 af[4], bfr[4];
#pragma unroll
        for (int i = 0; i < 4; i++)
            af[i] = *(const f16x8*)&As[(wm * 64 + i * 16 + lm) * 32 + quad * 8];
#pragma unroll
        for (int j = 0; j < 4; j++)
            bfr[j] = *(const f16x8*)&Bs[(wn * 64 + j * 16 + lm) * 32 + quad * 8];
#pragma unroll
        for (int i = 0; i < 4; i++)
#pragma unroll
            for (int j = 0; j < 4; j++)
                acc[i][j] = __builtin_amdgcn_mfma_f32_16x16x32_f16(af[i], bfr[j],
                                                                   acc[i][j], 0, 0, 0);
    }

#pragma unroll
    for (int i = 0; i < 4; i++) {
#pragma unroll
        for (int j = 0; j < 4; j++) {
            const int n = tn0 + wn * 64 + j * 16 + lm;
            const float bv = bias[n];
#pragma unroll
            for (int r = 0; r < 4; r++) {
                const int m = tm0 + wm * 64 + i * 16 + quad * 4 + r;
                Cout[(size_t)m * E_ + n] = acc[i][j][r] + bv;
            }
        }
    }
}

// ---------------------------------------------------------------- launch
extern "C" void kernel_launch(void* const* d_in, const int* in_sizes, int n_in,
                              void* d_out, int out_size, void* d_ws, size_t ws_size,
                              hipStream_t stream) {
    const float* x     = (const float*)d_in[0];
    const float* w_qkv = (const float*)d_in[1];
    const float* b_qkv = (const float*)d_in[2];
    const float* w_out = (const float*)d_in[3];
    const float* b_out = (const float*)d_in[4];
    float* out = (float*)d_out;

    char* ws = (char*)d_ws;
    f16* xb  = (f16*)ws; ws += (size_t)S_ * E_ * 2;
    f16* wqb = (f16*)ws; ws += (size_t)3 * E_ * E_ * 2;
    f16* wob = (f16*)ws; ws += (size_t)E_ * E_ * 2;
    f16* Qm  = (f16*)ws; ws += (size_t)H_ * S_ * D_ * 2;
    f16* Km  = (f16*)ws; ws += (size_t)H_ * S_ * D_ * 2;
    f16* VTm = (f16*)ws; ws += (size_t)H_ * D_ * S_ * 2;
    f16* Om  = (f16*)ws; ws += (size_t)S_ * E_ * 2;

    // attn partials reuse the xb+wqb region (32MB, dead after gemm_qkv):
    // Opart 1280 units x 64 rows x 128 d (f16) = 20MB; Mlp 1280 x 64 float2 = 640KB.
    f16*    Opart = (f16*)d_ws;
    float2* Mlp   = (float2*)((char*)d_ws + (20u << 20));

    cvt_f32_f16<<<4096, 256, 0, stream>>>(x, xb, S_ * E_);
    cvt_f32_f16<<<12288, 256, 0, stream>>>(w_qkv, wqb, 3 * E_ * E_);
    cvt_f32_f16<<<4096, 256, 0, stream>>>(w_out, wob, E_ * E_);
    gemm_qkv<<<dim3(48, 16), 256, 0, stream>>>(xb, wqb, b_qkv, Qm, Km, VTm);
    attn_part<<<1280, 256, 0, stream>>>(Qm, Km, VTm, Om, Opart, Mlp);
    attn_merge<<<3072, 256, 0, stream>>>(Opart, Mlp, Om);
    gemm_out<<<dim3(16, 16), 256, 0, stream>>>(Om, wob, b_out, out);
}